// Round 9
// baseline (214.229 us; speedup 1.0000x reference)
//
#include <hip/hip_runtime.h>

#define NRAYS 8192
typedef const float* fpp;
typedef unsigned int uint;

typedef short bf16x8 __attribute__((ext_vector_type(8)));
typedef int   i32x4  __attribute__((ext_vector_type(4)));
typedef int   i32x2  __attribute__((ext_vector_type(2)));
typedef float f32x4  __attribute__((ext_vector_type(4)));
typedef float f32x2  __attribute__((ext_vector_type(2)));

__device__ __forceinline__ short f2bf(float f) {           // RNE fp32->bf16
  unsigned u = __float_as_uint(f);
  return (short)((u + 0x7FFFu + ((u >> 16) & 1u)) >> 16);
}
// pack2: low short = bf16(a), high short = bf16(b)
__device__ __forceinline__ int pk2(float a, float b) {
  return (int)__builtin_amdgcn_perm(__float_as_uint(b) + 0x8000u,
                                    __float_as_uint(a) + 0x8000u, 0x07060302u);
}
__device__ __forceinline__ f32x4 MFMA(bf16x8 a, bf16x8 b, f32x4 c) {
  return __builtin_amdgcn_mfma_f32_16x16x32_bf16(a, b, c, 0, 0, 0);
}
__device__ __forceinline__ float waveAllSum(float v) {
#pragma unroll
  for (int off = 32; off > 0; off >>= 1) v += __shfl_xor(v, off, 64);
  return v;
}

// output layout (flat fp32): image[8192,3]@0 depth@24576 dvar@32768 coord@40960
// rgbs[8192,256,3]@65536 clip[8192,32]@6356992
#define OFF_IMG   0
#define OFF_DEPTH 24576
#define OFF_VAR   32768
#define OFF_COORD 40960
#define OFF_RGBS  65536
#define OFF_CLIP  6356992

// ---------------- prep kernel: pack weight fragments into d_ws ----------------
// ws layout (uint4): a2[lane*2+kt] @0..127, c1a[lane*4+ht] @128..383, k1a @384..639
__global__ void prep_kernel(fpp Wd2, fpp Wc1, fpp Wk1, uint4* ws) {
  const int lane = threadIdx.x & 63;
  const int c16 = lane & 15, o = lane >> 4;
  uint t[4];
#pragma unroll
  for (int kt = 0; kt < 2; kt++) {
#pragma unroll
    for (int q = 0; q < 4; q++) {
      float w0 = Wd2[(32 * kt + 8 * o + 2 * q) * 16 + c16];
      float w1 = Wd2[(32 * kt + 8 * o + 2 * q + 1) * 16 + c16];
      t[q] = ((uint)(unsigned short)f2bf(w1) << 16) | (uint)(unsigned short)f2bf(w0);
    }
    ws[lane * 2 + kt] = make_uint4(t[0], t[1], t[2], t[3]);
  }
#pragma unroll
  for (int ht = 0; ht < 4; ht++) {
    uint tc[4], tk[4];
#pragma unroll
    for (int q = 0; q < 4; q++) {
      uint pc = 0, pkk = 0;
#pragma unroll
      for (int half = 0; half < 2; half++) {
        int h = 16 * ht + c16, k = 8 * o + 2 * q + half;
        float wc = 0.f, wk = 0.f;
        if (k >= 1 && k <= 15) wc = Wc1[(k + 2) * 64 + h];
        else if (k >= 16 && k <= 18) wc = Wc1[(k - 16) * 64 + h];
        if (k == 0) wk = Wk1[15 * 64 + h];
        else if (k <= 15) wk = Wk1[(k - 1) * 64 + h];
        pc  |= (uint)(unsigned short)f2bf(wc) << (16 * half);
        pkk |= (uint)(unsigned short)f2bf(wk) << (16 * half);
      }
      tc[q] = pc; tk[q] = pkk;
    }
    ws[128 + lane * 4 + ht] = make_uint4(tc[0], tc[1], tc[2], tc[3]);
    ws[384 + lane * 4 + ht] = make_uint4(tk[0], tk[1], tk[2], tk[3]);
  }
}

// 2 rays per block, 2 waves per ray (wave wv handles samples [128*wv, 128*wv+128)).
template <bool PREP>
__global__ __launch_bounds__(256) void nerf_kernel(
    fpp rays_o, fpp rays_d, fpp dnorms,
    fpp Wd1, fpp bd1, fpp Wd2, fpp bd2,
    fpp Wc1, fpp bc1, fpp Wc2, fpp bc2,
    fpp Wk1, fpp bk1, fpp Wk2, fpp bk2,
    const uint4* wsp, float* out)
{
  __shared__ short  geoA[2][256][8];   // cols 0-7 (sigma,geo0-6)
  __shared__ short  geoB[2][256][8];   // cols 8-15 (geo7-14)
  __shared__ float  tmp[2][256];       // phase1: sigma; scan onward: wm
  __shared__ float4 wc2s[64];          // {Wc2[h][0..2],0}
  __shared__ __align__(16) float sBd2[16];
  __shared__ __align__(16) float sBc1[64];
  __shared__ __align__(16) float sBk1[64];
  __shared__ float  scanP[2][2];       // wave total products
  __shared__ float  redbuf[2][2][8];   // {ws,swz,cx,cy,cz,var}
  __shared__ float  imgbuf[2][2][4];
  __shared__ __align__(16) float gbuf[2][2][64];

  const int tid = threadIdx.x;
  if (tid < 64) {
    wc2s[tid] = make_float4(Wc2[tid * 3], Wc2[tid * 3 + 1], Wc2[tid * 3 + 2], 0.f);
    sBc1[tid] = bc1[tid];
    sBk1[tid] = bk1[tid];
    if (tid < 16) sBd2[tid] = bd2[tid];
  }
  __syncthreads();

  const int wave = tid >> 6, lane = tid & 63;
  const int rw = wave >> 1, wv = wave & 1;
  const int c16 = lane & 15, o = lane >> 4;
  const int ray = blockIdx.x * 2 + rw;
  const int S0 = 128 * wv;

  // ---------------- ray setup ----------------
  const float ox = rays_o[ray * 3 + 0], oy = rays_o[ray * 3 + 1], oz = rays_o[ray * 3 + 2];
  const float dx = rays_d[ray * 3 + 0], dy = rays_d[ray * 3 + 1], dz = rays_d[ray * 3 + 2];
  const float dn = dnorms[ray];
  const float ixr = 1.f / dx, iyr = 1.f / dy, izr = 1.f / dz;
  float t1x = (-1.f - ox) * ixr, t2x = (1.f - ox) * ixr;
  float t1y = (-1.f - oy) * iyr, t2y = (1.f - oy) * iyr;
  float t1z = (-1.f - oz) * izr, t2z = (1.f - oz) * izr;
  float nearv = fmaxf(fmaxf(fminf(t1x, t2x), fminf(t1y, t2y)), fminf(t1z, t2z));
  nearv = fmaxf(nearv, 0.2f);
  float farv = fminf(fminf(fmaxf(t1x, t2x), fmaxf(t1y, t2y)), fmaxf(t1z, t2z));
  farv = fmaxf(farv, nearv + 0.0001f);
  const float span = farv - nearv;

  // ---------------- weight fragments ----------------
  bf16x8 a2[2], c1a[4], k1a[4];
  if (PREP) {
#pragma unroll
    for (int kt = 0; kt < 2; kt++) a2[kt] = __builtin_bit_cast(bf16x8, wsp[lane * 2 + kt]);
#pragma unroll
    for (int ht = 0; ht < 4; ht++) {
      c1a[ht] = __builtin_bit_cast(bf16x8, wsp[128 + lane * 4 + ht]);
      k1a[ht] = __builtin_bit_cast(bf16x8, wsp[384 + lane * 4 + ht]);
    }
  } else {
#pragma unroll
    for (int kt = 0; kt < 2; kt++)
#pragma unroll
      for (int j = 0; j < 8; j++)
        a2[kt][j] = f2bf(Wd2[(32 * kt + 8 * o + j) * 16 + c16]);
#pragma unroll
    for (int ht = 0; ht < 4; ht++)
#pragma unroll
      for (int j = 0; j < 8; j++) {
        int h = 16 * ht + c16, k = 8 * o + j;
        float wc = 0.f, wk = 0.f;
        if (k >= 1 && k <= 15) wc = Wc1[(k + 2) * 64 + h];
        else if (k >= 16 && k <= 18) wc = Wc1[(k - 16) * 64 + h];
        if (k == 0) wk = Wk1[15 * 64 + h];
        else if (k <= 15) wk = Wk1[(k - 1) * 64 + h];
        c1a[ht][j] = f2bf(wc);
        k1a[ht][j] = f2bf(wk);
      }
  }

  // A1 linearized: h1 = relu(p + q*z), h = 32*kt + 8*o + j
  float p1[16], q1[16];
#pragma unroll
  for (int kt = 0; kt < 2; kt++)
#pragma unroll
    for (int j = 0; j < 8; j++) {
      int h = 32 * kt + 8 * o + j;
      float w0 = Wd1[h], w1 = Wd1[64 + h], w2 = Wd1[128 + h];
      p1[8 * kt + j] = fmaf(w0, ox, fmaf(w1, oy, fmaf(w2, oz, bd1[h])));
      q1[8 * kt + j] = fmaf(w0, dx, fmaf(w1, dy, w2 * dz));
    }

  // dirs fragment for B1a (K rows 16..18 live on o==2)
  bf16x8 dfr;
#pragma unroll
  for (int j = 0; j < 8; j++)
    dfr[j] = (o == 2 && j < 3) ? f2bf(j == 0 ? dx : (j == 1 ? dy : dz)) : (short)0;
  const bf16x8 zf = {0, 0, 0, 0, 0, 0, 0, 0};

  // ================ PHASE 1: density MLP (8 tiles of 16 samples) =============
#pragma unroll 1
  for (int mt = 0; mt < 8; mt++) {
    const int s = S0 + mt * 16 + c16;
    const float zt = nearv + span * ((float)s * (1.f / 255.f));
    bf16x8 h1f[2];
#pragma unroll
    for (int kt = 0; kt < 2; kt++) {
      i32x4 tv;
#pragma unroll
      for (int q = 0; q < 4; q++) {
        float a = fmaxf(fmaf(q1[8 * kt + 2 * q],     zt, p1[8 * kt + 2 * q]),     0.f);
        float b = fmaxf(fmaf(q1[8 * kt + 2 * q + 1], zt, p1[8 * kt + 2 * q + 1]), 0.f);
        tv[q] = pk2(a, b);
      }
      h1f[kt] = __builtin_bit_cast(bf16x8, tv);
    }
    f32x4 acc = *(f32x4*)&sBd2[4 * o];
    acc = MFMA(a2[0], h1f[0], acc);
    acc = MFMA(a2[1], h1f[1], acc);
    float sgm = __expf(acc[0]);                    // valid on o==0
    i32x2 pkv;
    pkv[0] = pk2((o == 0) ? sgm : acc[0], acc[1]);
    pkv[1] = pk2(acc[2], acc[3]);
    if (o < 2) *(i32x2*)&geoA[rw][s][4 * o] = pkv;
    else       *(i32x2*)&geoB[rw][s][4 * (o - 2)] = pkv;
    if (o == 0) tmp[rw][s] = sgm;
  }

  // ================ two-level transmittance scan =============================
  float z0, z1, wm0, wm1;
  float ws, depth, var;
  {
    f32x2 sgv = *(f32x2*)&tmp[rw][S0 + 2 * lane];
    const int t0 = S0 + 2 * lane;
    z0 = nearv + span * ((float)t0 * (1.f / 255.f));
    z1 = nearv + span * ((float)(t0 + 1) * (1.f / 255.f));
    float d0 = span * (1.f / 255.f);
    float d1 = (t0 + 1 < 255) ? d0 : span * (1.f / 256.f);
    float a0 = 1.f - __expf(-d0 * sgv[0]);
    float a1 = 1.f - __expf(-d1 * sgv[1]);
    float v0 = 1.f - a0 + 1e-15f, v1 = 1.f - a1 + 1e-15f;
    float lprod = v0 * v1;
    float ip = lprod;
#pragma unroll
    for (int off = 1; off < 64; off <<= 1) {
      float u = __shfl_up(ip, off, 64);
      if (lane >= off) ip *= u;
    }
    float E = __shfl_up(ip, 1, 64);
    if (lane == 0) E = 1.f;
    float Pw = __shfl(ip, 63, 64);
    if (lane == 0) scanP[rw][wv] = Pw;
    __syncthreads();                                   // S1
    if (wv == 1) E *= scanP[rw][0];
    float w0_ = a0 * E, w1_ = a1 * E * v0;
    wm0 = (w0_ > 0.0001f) ? w0_ : 0.f;
    wm1 = (w1_ > 0.0001f) ? w1_ : 0.f;
    f32x2 wmv2 = {wm0, wm1};
    *(f32x2*)&tmp[rw][S0 + 2 * lane] = wmv2;           // overwrite sigma with wm

    float wsp_ = wm0 + wm1;
    float swzp = fmaf(wm0, z0, wm1 * z1);
    float xc0 = fminf(fmaxf(fmaf(dx, z0, ox), -1.f), 1.f);
    float yc0 = fminf(fmaxf(fmaf(dy, z0, oy), -1.f), 1.f);
    float zc0 = fminf(fmaxf(fmaf(dz, z0, oz), -1.f), 1.f);
    float xc1 = fminf(fmaxf(fmaf(dx, z1, ox), -1.f), 1.f);
    float yc1 = fminf(fmaxf(fmaf(dy, z1, oy), -1.f), 1.f);
    float zc1 = fminf(fmaxf(fmaf(dz, z1, oz), -1.f), 1.f);
    float cxp = fmaf(wm0, xc0, wm1 * xc1);
    float cyp = fmaf(wm0, yc0, wm1 * yc1);
    float czp = fmaf(wm0, zc0, wm1 * zc1);
    wsp_ = waveAllSum(wsp_); swzp = waveAllSum(swzp);
    cxp = waveAllSum(cxp); cyp = waveAllSum(cyp); czp = waveAllSum(czp);
    if (lane == 0) {
      redbuf[rw][wv][0] = wsp_; redbuf[rw][wv][1] = swzp;
      redbuf[rw][wv][2] = cxp;  redbuf[rw][wv][3] = cyp; redbuf[rw][wv][4] = czp;
    }
    __syncthreads();                                   // S2
    ws = redbuf[rw][0][0] + redbuf[rw][1][0];
    float swz = redbuf[rw][0][1] + redbuf[rw][1][1];
    depth = swz / dn;
    float dd0 = depth - z0 / dn, dd1 = depth - z1 / dn;
    float varp = fmaf(wm0, dd0 * dd0, wm1 * (dd1 * dd1));
    varp = waveAllSum(varp);
    if (lane == 0) redbuf[rw][wv][5] = varp;
    __syncthreads();                                   // S3
    if (wv == 0 && lane == 0) {
      var = redbuf[rw][0][5] + redbuf[rw][1][5];
      out[OFF_DEPTH + ray] = depth;
      out[OFF_VAR + ray]   = var;
      out[OFF_COORD + ray * 3 + 0] = redbuf[rw][0][2] + redbuf[rw][1][2];
      out[OFF_COORD + ray * 3 + 1] = redbuf[rw][0][3] + redbuf[rw][1][3];
      out[OFF_COORD + ray * 3 + 2] = redbuf[rw][0][4] + redbuf[rw][1][4];
    }
  }

  // ================ PHASE 2: color + clip MLPs (8 tiles) =====================
  float imgp = 0.f;
  float gp[4][4];
#pragma unroll
  for (int ht = 0; ht < 4; ht++)
#pragma unroll
    for (int r = 0; r < 4; r++) gp[ht][r] = 0.f;

#pragma unroll 1
  for (int mt = 0; mt < 8; mt++) {
    const int s = S0 + mt * 16 + c16;
    bf16x8 gfr = zf;
    if (o == 0)      gfr = *(bf16x8*)&geoA[rw][s][0];
    else if (o == 1) gfr = *(bf16x8*)&geoB[rw][s][0];
    const float wmv = tmp[rw][s];
    // ---- B1a ----
    bf16x8 bfr1 = (o == 2) ? dfr : gfr;
    float r0 = 0.f, r1 = 0.f, r2 = 0.f;
#pragma unroll
    for (int ht = 0; ht < 4; ht++) {
      f32x4 hc = MFMA(c1a[ht], bfr1, *(f32x4*)&sBc1[16 * ht + 4 * o]);
#pragma unroll
      for (int r = 0; r < 4; r++) {
        float hv = fmaxf(hc[r], 0.f);
        float4 w2 = wc2s[16 * ht + 4 * o + r];
        r0 = fmaf(hv, w2.x, r0); r1 = fmaf(hv, w2.y, r1); r2 = fmaf(hv, w2.z, r2);
      }
    }
    r0 += __shfl_xor(r0, 16, 64); r0 += __shfl_xor(r0, 32, 64);
    r1 += __shfl_xor(r1, 16, 64); r1 += __shfl_xor(r1, 32, 64);
    r2 += __shfl_xor(r2, 16, 64); r2 += __shfl_xor(r2, 32, 64);
    // ---- B1b epilogue ----
    {
      float rq = (o == 0) ? (r0 + bc2[0]) : ((o == 1) ? (r1 + bc2[1]) : (r2 + bc2[2]));
      float sgd = __builtin_amdgcn_rcpf(1.f + __expf(-rq));
      sgd = (wmv > 0.f) ? sgd : 0.f;
      if (o < 3) {
        out[OFF_RGBS + ((long)ray * 256 + s) * 3 + o] = sgd;
        imgp = fmaf(wmv, sgd, imgp);
      }
    }
    // ---- B2a ----
#pragma unroll
    for (int ht = 0; ht < 4; ht++) {
      f32x4 hk = MFMA(k1a[ht], gfr, *(f32x4*)&sBk1[16 * ht + 4 * o]);
#pragma unroll
      for (int r = 0; r < 4; r++)
        gp[ht][r] = fmaf(wmv, fmaxf(hk[r], 0.f), gp[ht][r]);
    }
  }

  // image partials: reduce within o-group, write channel partials + g partials
  imgp += __shfl_xor(imgp, 1, 64);
  imgp += __shfl_xor(imgp, 2, 64);
  imgp += __shfl_xor(imgp, 4, 64);
  imgp += __shfl_xor(imgp, 8, 64);
  if (c16 == 0 && o < 3) imgbuf[rw][wv][o] = imgp;
#pragma unroll
  for (int ht = 0; ht < 4; ht++)
#pragma unroll
    for (int r = 0; r < 4; r++) {
      float g = gp[ht][r];
      g += __shfl_xor(g, 1, 64); g += __shfl_xor(g, 2, 64);
      g += __shfl_xor(g, 4, 64); g += __shfl_xor(g, 8, 64);
      gp[ht][r] = g;
    }
  if (c16 == 0) {
#pragma unroll
    for (int ht = 0; ht < 4; ht++) {
      f32x4 gv = {gp[ht][0], gp[ht][1], gp[ht][2], gp[ht][3]};
      *(f32x4*)&gbuf[rw][wv][16 * ht + 4 * o] = gv;
    }
  }
  __syncthreads();                                     // S4

  if (wv == 0) {
    if (lane == 0) {
      out[OFF_IMG + ray * 3 + 0] = imgbuf[rw][0][0] + imgbuf[rw][1][0] + (1.f - ws);
      out[OFF_IMG + ray * 3 + 1] = imgbuf[rw][0][1] + imgbuf[rw][1][1] + (1.f - ws);
      out[OFF_IMG + ray * 3 + 2] = imgbuf[rw][0][2] + imgbuf[rw][1][2] + (1.f - ws);
    }
    // ---- B2b: clip = g_tot @ Wk2 + ws*bk2 (wave 0 of each ray) ----
    float gt[4][4];
#pragma unroll
    for (int ht = 0; ht < 4; ht++) {
      f32x4 ga = *(f32x4*)&gbuf[rw][0][16 * ht + 4 * o];
      f32x4 gb = *(f32x4*)&gbuf[rw][1][16 * ht + 4 * o];
#pragma unroll
      for (int r = 0; r < 4; r++) gt[ht][r] = ga[r] + gb[r];
    }
    const int k2 = 2 * c16;
    float cp0 = 0.f, cp1 = 0.f;
#pragma unroll
    for (int ht = 0; ht < 4; ht++)
#pragma unroll
      for (int r = 0; r < 4; r++) {
        int h = 16 * ht + 4 * o + r;
        cp0 = fmaf(gt[ht][r], Wk2[h * 32 + k2], cp0);
        cp1 = fmaf(gt[ht][r], Wk2[h * 32 + k2 + 1], cp1);
      }
    cp0 += __shfl_xor(cp0, 16, 64); cp0 += __shfl_xor(cp0, 32, 64);
    cp1 += __shfl_xor(cp1, 16, 64); cp1 += __shfl_xor(cp1, 32, 64);
    cp0 = fmaf(ws, bk2[k2], cp0);
    cp1 = fmaf(ws, bk2[k2 + 1], cp1);
    if (lane < 16) {
      out[OFF_CLIP + ray * 32 + k2]     = cp0;
      out[OFF_CLIP + ray * 32 + k2 + 1] = cp1;
    }
  }
}

extern "C" void kernel_launch(void* const* d_in, const int* in_sizes, int n_in,
                              void* d_out, int out_size, void* d_ws, size_t ws_size,
                              hipStream_t stream) {
  const bool prep = (ws_size >= 10240);
  if (prep) {
    prep_kernel<<<1, 64, 0, stream>>>((fpp)d_in[5], (fpp)d_in[7], (fpp)d_in[11],
                                      (uint4*)d_ws);
    nerf_kernel<true><<<NRAYS / 2, 256, 0, stream>>>(
        (fpp)d_in[0], (fpp)d_in[1], (fpp)d_in[2],
        (fpp)d_in[3], (fpp)d_in[4], (fpp)d_in[5], (fpp)d_in[6],
        (fpp)d_in[7], (fpp)d_in[8], (fpp)d_in[9], (fpp)d_in[10],
        (fpp)d_in[11], (fpp)d_in[12], (fpp)d_in[13], (fpp)d_in[14],
        (const uint4*)d_ws, (float*)d_out);
  } else {
    nerf_kernel<false><<<NRAYS / 2, 256, 0, stream>>>(
        (fpp)d_in[0], (fpp)d_in[1], (fpp)d_in[2],
        (fpp)d_in[3], (fpp)d_in[4], (fpp)d_in[5], (fpp)d_in[6],
        (fpp)d_in[7], (fpp)d_in[8], (fpp)d_in[9], (fpp)d_in[10],
        (fpp)d_in[11], (fpp)d_in[12], (fpp)d_in[13], (fpp)d_in[14],
        (const uint4*)d_ws, (float*)d_out);
  }
}

// Round 10
// 157.838 us; speedup vs baseline: 1.3573x; 1.3573x over previous
//
#include <hip/hip_runtime.h>

#define NRAYS 8192
typedef const float* fpp;
typedef unsigned int uint;

typedef short bf16x8 __attribute__((ext_vector_type(8)));
typedef int   i32x4  __attribute__((ext_vector_type(4)));
typedef int   i32x2  __attribute__((ext_vector_type(2)));
typedef float f32x4  __attribute__((ext_vector_type(4)));

__device__ __forceinline__ short f2bf(float f) {           // RNE fp32->bf16
  unsigned u = __float_as_uint(f);
  return (short)((u + 0x7FFFu + ((u >> 16) & 1u)) >> 16);
}
// pack2: low short = bf16(a), high short = bf16(b)
__device__ __forceinline__ int pk2(float a, float b) {
  return (int)__builtin_amdgcn_perm(__float_as_uint(b) + 0x8000u,
                                    __float_as_uint(a) + 0x8000u, 0x07060302u);
}
__device__ __forceinline__ f32x4 MFMA(bf16x8 a, bf16x8 b, f32x4 c) {
  return __builtin_amdgcn_mfma_f32_16x16x32_bf16(a, b, c, 0, 0, 0);
}
__device__ __forceinline__ float waveAllSum(float v) {
#pragma unroll
  for (int off = 32; off > 0; off >>= 1) v += __shfl_xor(v, off, 64);
  return v;
}

// output layout (flat fp32): image[8192,3]@0 depth@24576 dvar@32768 coord@40960
// rgbs[8192,256,3]@65536 clip[8192,32]@6356992
#define OFF_IMG   0
#define OFF_DEPTH 24576
#define OFF_VAR   32768
#define OFF_COORD 40960
#define OFF_RGBS  65536
#define OFF_CLIP  6356992

// hcb row stride in shorts (144B rows: 16B-aligned, spreads b128 start banks)
#define HSTR 72

// ---------------- prep kernel: pack weight fragments into d_ws ----------------
// ws layout (uint4): a2 @0..127, c1a @128..383, k1a @384..639, a_rgb @640..767
__global__ void prep_kernel(fpp Wd2, fpp Wc1, fpp Wk1, fpp Wc2, fpp bc1, fpp bk1,
                            uint4* ws) {
  const int lane = threadIdx.x & 63;
  const int c16 = lane & 15, o = lane >> 4;
  uint t[4];
#pragma unroll
  for (int kt = 0; kt < 2; kt++) {
#pragma unroll
    for (int q = 0; q < 4; q++) {
      float w0 = Wd2[(32 * kt + 8 * o + 2 * q) * 16 + c16];
      float w1 = Wd2[(32 * kt + 8 * o + 2 * q + 1) * 16 + c16];
      t[q] = ((uint)(unsigned short)f2bf(w1) << 16) | (uint)(unsigned short)f2bf(w0);
    }
    ws[lane * 2 + kt] = make_uint4(t[0], t[1], t[2], t[3]);
  }
#pragma unroll
  for (int ht = 0; ht < 4; ht++) {
    uint tc[4], tk[4];
#pragma unroll
    for (int q = 0; q < 4; q++) {
      uint pc = 0, pkk = 0;
#pragma unroll
      for (int half = 0; half < 2; half++) {
        int h = 16 * ht + c16, k = 8 * o + 2 * q + half;
        float wc = 0.f, wk = 0.f;
        if (k >= 1 && k <= 15) wc = Wc1[(k + 2) * 64 + h];
        else if (k >= 16 && k <= 18) wc = Wc1[(k - 16) * 64 + h];
        else if (k == 19) wc = bc1[h];                    // bias row
        if (k == 0) wk = Wk1[15 * 64 + h];
        else if (k <= 15) wk = Wk1[(k - 1) * 64 + h];
        else if (k == 16) wk = bk1[h];                    // bias row
        pc  |= (uint)(unsigned short)f2bf(wc) << (16 * half);
        pkk |= (uint)(unsigned short)f2bf(wk) << (16 * half);
      }
      tc[q] = pc; tk[q] = pkk;
    }
    ws[128 + lane * 4 + ht] = make_uint4(tc[0], tc[1], tc[2], tc[3]);
    ws[384 + lane * 4 + ht] = make_uint4(tk[0], tk[1], tk[2], tk[3]);
  }
  // a_rgb: A[m=ch][k=h]: lane holds m=c16 (ch<3 valid), k = 32*kt + 8*o + j
#pragma unroll
  for (int kt = 0; kt < 2; kt++) {
#pragma unroll
    for (int q = 0; q < 4; q++) {
      uint p = 0;
#pragma unroll
      for (int half = 0; half < 2; half++) {
        int h = 32 * kt + 8 * o + 2 * q + half;
        float w = (c16 < 3) ? Wc2[h * 3 + c16] : 0.f;
        p |= (uint)(unsigned short)f2bf(w) << (16 * half);
      }
      t[q] = p;
    }
    ws[640 + lane * 2 + kt] = make_uint4(t[0], t[1], t[2], t[3]);
  }
}

template <bool PREP>
__global__ __launch_bounds__(256) void nerf_kernel(
    fpp rays_o, fpp rays_d, fpp dnorms,
    fpp Wd1, fpp bd1, fpp Wd2, fpp bd2,
    fpp Wc1, fpp bc1, fpp Wc2, fpp bc2,
    fpp Wk1, fpp bk1, fpp Wk2, fpp bk2,
    const uint4* wsp, float* out)
{
  __shared__ short  geoA[4][256][8];   // cols 0-7 (sigma,geo0-6)
  __shared__ short  geoB[4][256][8];   // cols 8-15 (geo7-14)
  __shared__ float  tmp[4][256];       // phase1: sigma; scan onward: wm
  __shared__ short  hcb[4][16][HSTR];  // per-wave HC staging (bf16)

  const int tid = threadIdx.x;
  const int wave = tid >> 6, lane = tid & 63;
  const int c16 = lane & 15, o = lane >> 4;
  const int ray = blockIdx.x * 4 + wave;

  // ---------------- ray setup ----------------
  const float ox = rays_o[ray * 3 + 0], oy = rays_o[ray * 3 + 1], oz = rays_o[ray * 3 + 2];
  const float dx = rays_d[ray * 3 + 0], dy = rays_d[ray * 3 + 1], dz = rays_d[ray * 3 + 2];
  const float dn = dnorms[ray];
  const float ixr = 1.f / dx, iyr = 1.f / dy, izr = 1.f / dz;
  float t1x = (-1.f - ox) * ixr, t2x = (1.f - ox) * ixr;
  float t1y = (-1.f - oy) * iyr, t2y = (1.f - oy) * iyr;
  float t1z = (-1.f - oz) * izr, t2z = (1.f - oz) * izr;
  float nearv = fmaxf(fmaxf(fminf(t1x, t2x), fminf(t1y, t2y)), fminf(t1z, t2z));
  nearv = fmaxf(nearv, 0.2f);
  float farv = fminf(fminf(fmaxf(t1x, t2x), fmaxf(t1y, t2y)), fmaxf(t1z, t2z));
  farv = fmaxf(farv, nearv + 0.0001f);
  const float span = farv - nearv;

  // ---------------- weight fragments ----------------
  bf16x8 a2[2], c1a[4], k1a[4], argb[2];
  if (PREP) {
#pragma unroll
    for (int kt = 0; kt < 2; kt++) {
      a2[kt]   = __builtin_bit_cast(bf16x8, wsp[lane * 2 + kt]);
      argb[kt] = __builtin_bit_cast(bf16x8, wsp[640 + lane * 2 + kt]);
    }
#pragma unroll
    for (int ht = 0; ht < 4; ht++) {
      c1a[ht] = __builtin_bit_cast(bf16x8, wsp[128 + lane * 4 + ht]);
      k1a[ht] = __builtin_bit_cast(bf16x8, wsp[384 + lane * 4 + ht]);
    }
  } else {
#pragma unroll
    for (int kt = 0; kt < 2; kt++)
#pragma unroll
      for (int j = 0; j < 8; j++) {
        a2[kt][j]   = f2bf(Wd2[(32 * kt + 8 * o + j) * 16 + c16]);
        argb[kt][j] = (c16 < 3) ? f2bf(Wc2[(32 * kt + 8 * o + j) * 3 + c16]) : (short)0;
      }
#pragma unroll
    for (int ht = 0; ht < 4; ht++)
#pragma unroll
      for (int j = 0; j < 8; j++) {
        int h = 16 * ht + c16, k = 8 * o + j;
        float wc = 0.f, wk = 0.f;
        if (k >= 1 && k <= 15) wc = Wc1[(k + 2) * 64 + h];
        else if (k >= 16 && k <= 18) wc = Wc1[(k - 16) * 64 + h];
        else if (k == 19) wc = bc1[h];
        if (k == 0) wk = Wk1[15 * 64 + h];
        else if (k <= 15) wk = Wk1[(k - 1) * 64 + h];
        else if (k == 16) wk = bk1[h];
        c1a[ht][j] = f2bf(wc);
        k1a[ht][j] = f2bf(wk);
      }
  }

  // A1 linearized + per-lane constants
  float p1[16], q1[16];
#pragma unroll
  for (int kt = 0; kt < 2; kt++)
#pragma unroll
    for (int j = 0; j < 8; j++) {
      int h = 32 * kt + 8 * o + j;
      float w0 = Wd1[h], w1 = Wd1[64 + h], w2 = Wd1[128 + h];
      p1[8 * kt + j] = fmaf(w0, ox, fmaf(w1, oy, fmaf(w2, oz, bd1[h])));
      q1[8 * kt + j] = fmaf(w0, dx, fmaf(w1, dy, w2 * dz));
    }
  f32x4 bd2v = {bd2[4 * o], bd2[4 * o + 1], bd2[4 * o + 2], bd2[4 * o + 3]};
  f32x4 bc2i = {0.f, 0.f, 0.f, 0.f};
  if (o == 0) { bc2i[0] = bc2[0]; bc2i[1] = bc2[1]; bc2i[2] = bc2[2]; }

  // dirs fragment for B1a (K rows 16..19 live on o==2; k=19 is the bias row)
  bf16x8 dfr;
#pragma unroll
  for (int j = 0; j < 8; j++)
    dfr[j] = (o == 2) ? ((j == 0) ? f2bf(dx) : (j == 1) ? f2bf(dy) :
                         (j == 2) ? f2bf(dz) : (j == 3) ? (short)0x3F80 : (short)0)
                      : (short)0;
  // B2a one-hot bias carrier for o==2 (k=16 row)
  bf16x8 k1one = {0, 0, 0, 0, 0, 0, 0, 0};
  k1one[0] = (short)0x3F80;
  const bf16x8 zf = {0, 0, 0, 0, 0, 0, 0, 0};
  const f32x4 zacc = {0.f, 0.f, 0.f, 0.f};

  // ================ PHASE 1: density MLP ====================================
#pragma unroll 1
  for (int mt = 0; mt < 16; mt++) {
    const int s = mt * 16 + c16;
    const float zt = nearv + span * ((float)s * (1.f / 255.f));
    bf16x8 h1f[2];
#pragma unroll
    for (int kt = 0; kt < 2; kt++) {
      i32x4 tv;
#pragma unroll
      for (int q = 0; q < 4; q++) {
        float a = fmaxf(fmaf(q1[8 * kt + 2 * q],     zt, p1[8 * kt + 2 * q]),     0.f);
        float b = fmaxf(fmaf(q1[8 * kt + 2 * q + 1], zt, p1[8 * kt + 2 * q + 1]), 0.f);
        tv[q] = pk2(a, b);
      }
      h1f[kt] = __builtin_bit_cast(bf16x8, tv);
    }
    f32x4 acc = bd2v;
    acc = MFMA(a2[0], h1f[0], acc);
    acc = MFMA(a2[1], h1f[1], acc);
    float sgm = __expf(acc[0]);                    // valid on o==0
    i32x2 pkv;
    pkv[0] = pk2((o == 0) ? sgm : acc[0], acc[1]);
    pkv[1] = pk2(acc[2], acc[3]);
    if (o < 2) *(i32x2*)&geoA[wave][s][4 * o] = pkv;
    else       *(i32x2*)&geoB[wave][s][4 * (o - 2)] = pkv;
    if (o == 0) tmp[wave][s] = sgm;
  }

  // ================ transmittance scan (t-layout fp32) =======================
  float z[4], wm[4];
  float ws, swz, depth, var, cx, cy, cz;
  {
    f32x4 sgv = *(f32x4*)&tmp[wave][lane * 4];
    float alpha[4], v[4], m[4];
#pragma unroll
    for (int i = 0; i < 4; i++) {
      int t = lane * 4 + i;
      z[i] = nearv + span * ((float)t * (1.f / 255.f));
      float delta = (t < 255) ? span * (1.f / 255.f) : span * (1.f / 256.f);
      alpha[i] = 1.f - __expf(-delta * sgv[i]);
      v[i] = 1.f - alpha[i] + 1e-15f;
    }
    m[0] = 1.f; m[1] = v[0]; m[2] = m[1] * v[1]; m[3] = m[2] * v[2];
    float ip = m[3] * v[3];
#pragma unroll
    for (int off = 1; off < 64; off <<= 1) {
      float u = __shfl_up(ip, off, 64);
      if (lane >= off) ip *= u;
    }
    float E = __shfl_up(ip, 1, 64);
    if (lane == 0) E = 1.f;
    ws = 0.f; swz = 0.f; cx = 0.f; cy = 0.f; cz = 0.f;
#pragma unroll
    for (int i = 0; i < 4; i++) {
      float w = alpha[i] * (E * m[i]);
      wm[i] = (w > 0.0001f) ? w : 0.f;
      ws += wm[i];
      swz = fmaf(wm[i], z[i], swz);
      float xc = fminf(fmaxf(fmaf(dx, z[i], ox), -1.f), 1.f);
      float yc = fminf(fmaxf(fmaf(dy, z[i], oy), -1.f), 1.f);
      float zc = fminf(fmaxf(fmaf(dz, z[i], oz), -1.f), 1.f);
      cx = fmaf(wm[i], xc, cx); cy = fmaf(wm[i], yc, cy); cz = fmaf(wm[i], zc, cz);
    }
    f32x4 wv4 = {wm[0], wm[1], wm[2], wm[3]};
    *(f32x4*)&tmp[wave][lane * 4] = wv4;           // overwrite sigma with wm
    ws = waveAllSum(ws); swz = waveAllSum(swz);
    cx = waveAllSum(cx); cy = waveAllSum(cy); cz = waveAllSum(cz);
    depth = swz / dn;
    var = 0.f;
#pragma unroll
    for (int i = 0; i < 4; i++) {
      float dd = depth - z[i] / dn;
      var = fmaf(wm[i], dd * dd, var);
    }
    var = waveAllSum(var);
  }
  if (lane == 0) {
    out[OFF_DEPTH + ray] = depth;
    out[OFF_VAR + ray]   = var;
    out[OFF_COORD + ray * 3 + 0] = cx;
    out[OFF_COORD + ray * 3 + 1] = cy;
    out[OFF_COORD + ray * 3 + 2] = cz;
  }

  // ================ PHASE 2: color + clip MLPs, fully MFMA ===================
  float ia0 = 0.f, ia1 = 0.f, ia2 = 0.f;          // image partials (o==0 lanes)
  float gp[4][4];
#pragma unroll
  for (int ht = 0; ht < 4; ht++)
#pragma unroll
    for (int r = 0; r < 4; r++) gp[ht][r] = 0.f;

#pragma unroll 1
  for (int mt = 0; mt < 16; mt++) {
    const int s = mt * 16 + c16;
    bf16x8 gfr = zf;
    if (o == 0)      gfr = *(bf16x8*)&geoA[wave][s][0];
    else if (o == 1) gfr = *(bf16x8*)&geoB[wave][s][0];
    const float wmv = tmp[wave][s];
    // ---- B1a: HC = Wc1'' @ CIN'' (bias via k=19) ----
    bf16x8 bfr1 = (o == 2) ? dfr : gfr;
#pragma unroll
    for (int ht = 0; ht < 4; ht++) {
      f32x4 hc = MFMA(c1a[ht], bfr1, zacc);
      i32x2 hp;
      hp[0] = pk2(fmaxf(hc[0], 0.f), fmaxf(hc[1], 0.f));
      hp[1] = pk2(fmaxf(hc[2], 0.f), fmaxf(hc[3], 0.f));
      *(i32x2*)&hcb[wave][c16][16 * ht + 4 * o] = hp;   // HC[h=16ht+4o..+3][s=c16]
    }
    // ---- B1b: rgb = Wc2^T @ relu(HC) via MFMA (K=64) ----
    bf16x8 hcf0 = *(bf16x8*)&hcb[wave][c16][8 * o];       // k=8o+j
    bf16x8 hcf1 = *(bf16x8*)&hcb[wave][c16][32 + 8 * o];  // k=32+8o+j
    f32x4 racc = bc2i;
    racc = MFMA(argb[0], hcf0, racc);
    racc = MFMA(argb[1], hcf1, racc);
    // D[ch=4o+r][s=c16]: channels live on o==0, r=0..2
    if (o == 0) {
      const long ro = OFF_RGBS + ((long)ray * 256 + s) * 3;
      float s0 = __builtin_amdgcn_rcpf(1.f + __expf(-racc[0]));
      float s1 = __builtin_amdgcn_rcpf(1.f + __expf(-racc[1]));
      float s2 = __builtin_amdgcn_rcpf(1.f + __expf(-racc[2]));
      const bool mk = (wmv > 0.f);
      s0 = mk ? s0 : 0.f; s1 = mk ? s1 : 0.f; s2 = mk ? s2 : 0.f;
      out[ro + 0] = s0; out[ro + 1] = s1; out[ro + 2] = s2;
      ia0 = fmaf(wmv, s0, ia0);
      ia1 = fmaf(wmv, s1, ia1);
      ia2 = fmaf(wmv, s2, ia2);
    }
    // ---- B2a: HK = Wk1'' @ KIN'' (bias via k=16 one-hot on o==2) ----
    bf16x8 kfr = (o == 2) ? k1one : gfr;
#pragma unroll
    for (int ht = 0; ht < 4; ht++) {
      f32x4 hk = MFMA(k1a[ht], kfr, zacc);
#pragma unroll
      for (int r = 0; r < 4; r++)
        gp[ht][r] = fmaf(wmv, fmaxf(hk[r], 0.f), gp[ht][r]);
    }
  }

  // image: reduce channel partials over c16 (o==0 lanes hold data)
#pragma unroll
  for (int off = 1; off < 16; off <<= 1) {
    ia0 += __shfl_xor(ia0, off, 64);
    ia1 += __shfl_xor(ia1, off, 64);
    ia2 += __shfl_xor(ia2, off, 64);
  }
  if (lane == 0) {
    out[OFF_IMG + ray * 3 + 0] = ia0 + (1.f - ws);
    out[OFF_IMG + ray * 3 + 1] = ia1 + (1.f - ws);
    out[OFF_IMG + ray * 3 + 2] = ia2 + (1.f - ws);
  }

  // ---- B2b: reduce g over samples, then clip = g @ Wk2 + ws*bk2 ----
#pragma unroll
  for (int ht = 0; ht < 4; ht++)
#pragma unroll
    for (int r = 0; r < 4; r++) {
      float g = gp[ht][r];
      g += __shfl_xor(g, 1, 64); g += __shfl_xor(g, 2, 64);
      g += __shfl_xor(g, 4, 64); g += __shfl_xor(g, 8, 64);
      gp[ht][r] = g;                 // g[h], h = 16*ht + 4*o + r
    }
  {
    const int k2 = 2 * c16;
    float cp0 = 0.f, cp1 = 0.f;
#pragma unroll
    for (int ht = 0; ht < 4; ht++)
#pragma unroll
      for (int r = 0; r < 4; r++) {
        int h = 16 * ht + 4 * o + r;
        cp0 = fmaf(gp[ht][r], Wk2[h * 32 + k2], cp0);
        cp1 = fmaf(gp[ht][r], Wk2[h * 32 + k2 + 1], cp1);
      }
    cp0 += __shfl_xor(cp0, 16, 64); cp0 += __shfl_xor(cp0, 32, 64);
    cp1 += __shfl_xor(cp1, 16, 64); cp1 += __shfl_xor(cp1, 32, 64);
    cp0 = fmaf(ws, bk2[k2], cp0);
    cp1 = fmaf(ws, bk2[k2 + 1], cp1);
    if (lane < 16) {
      out[OFF_CLIP + ray * 32 + k2]     = cp0;
      out[OFF_CLIP + ray * 32 + k2 + 1] = cp1;
    }
  }
}

extern "C" void kernel_launch(void* const* d_in, const int* in_sizes, int n_in,
                              void* d_out, int out_size, void* d_ws, size_t ws_size,
                              hipStream_t stream) {
  const bool prep = (ws_size >= 12288);
  if (prep) {
    prep_kernel<<<1, 64, 0, stream>>>((fpp)d_in[5], (fpp)d_in[7], (fpp)d_in[11],
                                      (fpp)d_in[9], (fpp)d_in[8], (fpp)d_in[12],
                                      (uint4*)d_ws);
    nerf_kernel<true><<<NRAYS / 4, 256, 0, stream>>>(
        (fpp)d_in[0], (fpp)d_in[1], (fpp)d_in[2],
        (fpp)d_in[3], (fpp)d_in[4], (fpp)d_in[5], (fpp)d_in[6],
        (fpp)d_in[7], (fpp)d_in[8], (fpp)d_in[9], (fpp)d_in[10],
        (fpp)d_in[11], (fpp)d_in[12], (fpp)d_in[13], (fpp)d_in[14],
        (const uint4*)d_ws, (float*)d_out);
  } else {
    nerf_kernel<false><<<NRAYS / 4, 256, 0, stream>>>(
        (fpp)d_in[0], (fpp)d_in[1], (fpp)d_in[2],
        (fpp)d_in[3], (fpp)d_in[4], (fpp)d_in[5], (fpp)d_in[6],
        (fpp)d_in[7], (fpp)d_in[8], (fpp)d_in[9], (fpp)d_in[10],
        (fpp)d_in[11], (fpp)d_in[12], (fpp)d_in[13], (fpp)d_in[14],
        (const uint4*)d_ws, (float*)d_out);
  }
}